// Round 7
// baseline (463.497 us; speedup 1.0000x reference)
//
#include <hip/hip_runtime.h>
#include <hip/hip_cooperative_groups.h>
#include <hip/hip_bf16.h>
#include <math.h>

namespace cg = cooperative_groups;

#define T_SEQ 2048
#define DM 1024
#define NH 16
#define DH 64
#define CHUNK 64
#define NCHUNK (T_SEQ / CHUNK)   // 32
#define NBLK 512                 // cooperative grid: 2 blocks/CU x 256 CUs

typedef __hip_bfloat16 bf16;
typedef __attribute__((ext_vector_type(8))) short short8;
typedef __attribute__((ext_vector_type(4))) short short4v;
typedef __attribute__((ext_vector_type(4))) float f32x4;

static __device__ __forceinline__ short f2b_bits(float f) {
  bf16 t = __float2bfloat16(f);
  short s;
  __builtin_memcpy(&s, &t, 2);
  return s;
}
static __device__ __forceinline__ float b2f(short s) {
  unsigned int u = ((unsigned int)(unsigned short)s) << 16;
  float f;
  __builtin_memcpy(&f, &u, 4);
  return f;
}
// gated ELU+1: elu(x)+1 = x>0 ? x+1 : exp(x)
static __device__ __forceinline__ float gelu1(float raw, float gate, float inv) {
  float x = raw * gate * inv;
  return x > 0.f ? x + 1.f : __expf(x);
}
static __device__ __forceinline__ void gload16(const void* g, void* l) {
  __builtin_amdgcn_global_load_lds((const __attribute__((address_space(1))) void*)g,
                                   (__attribute__((address_space(3))) void*)l, 16, 0, 0);
}

struct P {
  const float *x, *ln_g, *ln_b, *qkv_w, *qkv_b, *gate_w, *gate_b, *proj_w, *proj_b;
  bf16 *xn, *xbf, *wqkv, *wgate, *wproj;
  short *Gb;
  float *ga;
  short *Qb, *Kb, *Vb;
  bf16 *Obuf;
  float *Skv, *Sk;
  float *out;
};

// LDS overlay: per-phase layouts share one 56.8 KB block (2 blocks/CU).
union SH {
  struct { short A[8192]; short B[8192]; } g;                    // 32 KB (gemm1)
  struct { float K[4352]; float V[4352]; } cs;                   // 34.8 KB (csum)
  struct { float Q[4352]; float V[4352]; float KP[4352];
           float denp[1024]; float skp[64]; float den[64]; } at; // 56.8 KB (attn)
  struct { short A[4096]; short B[4096]; } pj;                   // 16 KB (proj)
  float lnred[8];
};

// ---------------------------------------------------------------------------
// Phase 0: grid-stride LayerNorm (+ zero ga) + weight fp32->bf16.
// ---------------------------------------------------------------------------
static __device__ void phase_prep(const P& p, int blk, SH& sh) {
  const int tid = threadIdx.x;
  if (blk < 8) p.ga[blk * 256 + tid] = 0.f;
  for (int row = blk; row < T_SEQ; row += NBLK) {
    const float* xr = p.x + (size_t)row * DM;
    float vals[4];
    float s = 0.f, s2 = 0.f;
#pragma unroll
    for (int i = 0; i < 4; i++) {
      float v = xr[tid + i * 256];
      vals[i] = v;
      s += v;
      s2 += v * v;
    }
#pragma unroll
    for (int m = 1; m < 64; m <<= 1) {
      s += __shfl_xor(s, m, 64);
      s2 += __shfl_xor(s2, m, 64);
    }
    const int wid = tid >> 6;
    if ((tid & 63) == 0) {
      sh.lnred[wid] = s;
      sh.lnred[4 + wid] = s2;
    }
    __syncthreads();
    s = sh.lnred[0] + sh.lnred[1] + sh.lnred[2] + sh.lnred[3];
    s2 = sh.lnred[4] + sh.lnred[5] + sh.lnred[6] + sh.lnred[7];
    __syncthreads();  // WAR guard before next iteration re-writes lnred
    const float mean = s * (1.f / DM);
    const float var = s2 * (1.f / DM) - mean * mean;
    const float rstd = rsqrtf(var + 1e-5f);
#pragma unroll
    for (int i = 0; i < 4; i++) {
      int idx = tid + i * 256;
      float v = (vals[i] - mean) * rstd * p.ln_g[idx] + p.ln_b[idx];
      p.xn[(size_t)row * DM + idx] = __float2bfloat16(v);
      p.xbf[(size_t)row * DM + idx] = __float2bfloat16(vals[i]);
    }
  }
  // weights: 5*DM*DM/4 float4 elems, stride = NBLK*256 -> exactly 10 iters
  constexpr int NQ = 3 * DM * DM / 4, NS = DM * DM / 4, N4 = 5 * DM * DM / 4;
  for (int i = blk * 256 + tid; i < N4; i += NBLK * 256) {
    const float* src;
    bf16* dst;
    int j;
    if (i < NQ) { src = p.qkv_w; dst = p.wqkv; j = i; }
    else if (i < NQ + NS) { src = p.gate_w; dst = p.wgate; j = i - NQ; }
    else { src = p.proj_w; dst = p.wproj; j = i - NQ - NS; }
    float4 v = ((const float4*)src)[j];
    short4v sv;
    sv.x = f2b_bits(v.x); sv.y = f2b_bits(v.y); sv.z = f2b_bits(v.z); sv.w = f2b_bits(v.w);
    *(short4v*)&dst[j * 4] = sv;
  }
}

// ---------------------------------------------------------------------------
// Phase 1: fused gate+qkv GEMM, tile 128x128, BK=64. blk: bx=blk&15 (m-tile),
// by=blk>>4 (0..7 gate, 8..31 qkv).
// ---------------------------------------------------------------------------
static __device__ void phase_gemm1(const P& p, int blk, SH& sh) {
  constexpr int K = 1024;
  const int tid = threadIdx.x;
  const int wid = tid >> 6, lane = tid & 63;
  const int wm = wid >> 1, wn = wid & 1;
  const int lm = lane & 15, quad = lane >> 4;

  const int bx = blk & 15, by = blk >> 4;
  const bool isGate = by < 8;
  const int m0 = bx * 128;
  const int n0 = isGate ? by * 128 : (by - 8) * 128;
  const short* Ag = (const short*)(isGate ? p.xbf : p.xn);
  const short* Wg = (const short*)(isGate ? p.wgate : p.wqkv);

  f32x4 zero = {0.f, 0.f, 0.f, 0.f};
  f32x4 acc[4][4];
#pragma unroll
  for (int i = 0; i < 4; i++)
#pragma unroll
    for (int j = 0; j < 4; j++) acc[i][j] = zero;

  for (int kb = 0; kb < K; kb += 64) {
    __syncthreads();
#pragma unroll
    for (int sec = 0; sec < 2; sec++) {
#pragma unroll
      for (int it = 0; it < 2; it++) {
        const int idx = it * 256 + tid;
        const int row = idx >> 2, seg = (idx & 3) * 8;
        gload16(&Ag[(size_t)(m0 + row) * K + kb + sec * 32 + seg],
                &sh.g.A[sec * 4096 + (it * 256 + wid * 64) * 8]);
        gload16(&Wg[(size_t)(n0 + row) * K + kb + sec * 32 + seg],
                &sh.g.B[sec * 4096 + (it * 256 + wid * 64) * 8]);
      }
    }
    __syncthreads();
#pragma unroll
    for (int sec = 0; sec < 2; sec++) {
      short8 afr[4], bfr[4];
#pragma unroll
      for (int i = 0; i < 4; i++) {
        afr[i] = *(const short8*)&sh.g.A[sec * 4096 + (wm * 64 + i * 16 + lm) * 32 + quad * 8];
        bfr[i] = *(const short8*)&sh.g.B[sec * 4096 + (wn * 64 + i * 16 + lm) * 32 + quad * 8];
      }
#pragma unroll
      for (int i = 0; i < 4; i++)
#pragma unroll
        for (int j = 0; j < 4; j++)
          acc[i][j] = __builtin_amdgcn_mfma_f32_16x16x32_bf16(afr[i], bfr[j], acc[i][j], 0, 0, 0);
    }
  }

  if (isGate) {
    float* red = (float*)sh.g.A;   // 128 rows x 32 slots = 16 KB
    __syncthreads();               // MFMA LDS reads done
#pragma unroll
    for (int i = 0; i < 4; i++) {
#pragma unroll
      for (int r = 0; r < 4; r++) {
        const int rowl = wm * 64 + i * 16 + quad * 4 + r;
        const int row = m0 + rowl;
        float rp = 0.f;
#pragma unroll
        for (int j = 0; j < 4; j++) {
          const int col = n0 + wn * 64 + j * 16 + lm;
          float v = acc[i][j][r] + p.gate_b[col];
          float sig = 1.f / (1.f + __expf(-v));
          p.Gb[(size_t)row * DM + col] = f2b_bits(sig);
          rp += sig;
        }
        red[rowl * 32 + wn * 16 + lm] = rp;
      }
    }
    __syncthreads();
    if (tid < 128) {
      float s = 0.f;
#pragma unroll
      for (int t2 = 0; t2 < 32; t2++) s += red[tid * 32 + t2];
      atomicAdd(&p.ga[m0 + tid], s);
    }
  } else {
#pragma unroll
    for (int i = 0; i < 4; i++) {
      const int rbase = m0 + wm * 64 + i * 16 + quad * 4;
#pragma unroll
      for (int j = 0; j < 4; j++) {
        const int col = n0 + wn * 64 + j * 16 + lm;
        const float bval = p.qkv_b[col];
#pragma unroll
        for (int r = 0; r < 4; r++) {
          const int row = rbase + r;
          const short bv = f2b_bits(acc[i][j][r] + bval);
          if (col < DM) {
            const int d = col;
            p.Qb[((size_t)(d >> 6) * T_SEQ + row) * DH + (d & 63)] = bv;
          } else if (col < 2 * DM) {
            const int d = col - DM;
            p.Kb[((size_t)(d >> 6) * T_SEQ + row) * DH + (d & 63)] = bv;
          } else {
            const int d = col - 2 * DM;
            p.Vb[((size_t)(d >> 6) * T_SEQ + row) * DH + (d & 63)] = bv;
          }
        }
      }
    }
  }
}

// ---------------------------------------------------------------------------
// Phase 2: per (h,c) Skv_c = Kg^T V (gating applied during staging), Sk_c.
// ---------------------------------------------------------------------------
static __device__ void phase_csum(const P& p, int b, SH& sh) {
  constexpr int STR = 68;
  const int h = b >> 5, c = b & 31;
  const int tid = threadIdx.x;
  const int ty = tid >> 4, tx = tid & 15;
  const int d0 = ty * 4, m0 = tx * 4;
  const int t0 = c * CHUNK;
  const size_t cb = ((size_t)h * T_SEQ + t0) * DH;
#pragma unroll
  for (int q = 0; q < 4; q++) {
    int f = q * 256 + tid, row = f >> 4, seg = (f & 15) * 4;
    const int t = t0 + row;
    short4v kr = *(const short4v*)&p.Kb[cb + row * 64 + seg];
    short4v gr = *(const short4v*)&p.Gb[(size_t)t * DM + h * 64 + seg];
    short4v vr = *(const short4v*)&p.Vb[cb + row * 64 + seg];
    const float inv = 1.f / (p.ga[t] * (1.f / DM) + 1e-5f);
    f32x4 kgv, vv;
#pragma unroll
    for (int e = 0; e < 4; e++) {
      kgv[e] = gelu1(b2f(kr[e]), b2f(gr[e]), inv);
      vv[e] = b2f(vr[e]);
    }
    *(f32x4*)&sh.cs.K[row * STR + seg] = kgv;
    *(f32x4*)&sh.cs.V[row * STR + seg] = vv;
  }
  __syncthreads();
  float acc[4][4] = {};
#pragma unroll 4
  for (int s = 0; s < 64; s++) {
    f32x4 kf = *(const f32x4*)&sh.cs.K[s * STR + d0];
    f32x4 vf = *(const f32x4*)&sh.cs.V[s * STR + m0];
#pragma unroll
    for (int i = 0; i < 4; i++)
#pragma unroll
      for (int j = 0; j < 4; j++) acc[i][j] += kf[i] * vf[j];
  }
  float* outp = p.Skv + (size_t)b * 4096;
#pragma unroll
  for (int i = 0; i < 4; i++) {
    f32x4 o = {acc[i][0], acc[i][1], acc[i][2], acc[i][3]};
    *(f32x4*)&outp[(d0 + i) * 64 + m0] = o;
  }
  if (tid < 64) {
    float ss = 0.f;
#pragma unroll 4
    for (int s = 0; s < 64; s++) ss += sh.cs.K[s * STR + tid];
    p.Sk[b * 64 + tid] = ss;
  }
  __syncthreads();  // protect LDS before next phase overlays it
}

// ---------------------------------------------------------------------------
// Phase 3: exclusive prefix over chunks; blocks 0..255 Skv, 256..259 Sk.
// ---------------------------------------------------------------------------
static __device__ void phase_scan(const P& p, int bid) {
  const int tid = threadIdx.x;
  if (bid < 256) {
    const int id = bid * 256 + tid;
    const int h = id >> 12, e = id & 4095;
    float* base = p.Skv + (size_t)h * NCHUNK * 4096 + e;
    float v[NCHUNK];
#pragma unroll
    for (int c = 0; c < NCHUNK; c++) v[c] = base[(size_t)c * 4096];
    float run = 0.f;
#pragma unroll
    for (int c = 0; c < NCHUNK; c++) {
      float t = v[c];
      base[(size_t)c * 4096] = run;
      run += t;
    }
  } else if (bid < 260) {
    const int id = (bid - 256) * 256 + tid;
    const int h = id >> 6, e = id & 63;
    float* base = p.Sk + (size_t)h * NCHUNK * 64 + e;
    float v[NCHUNK];
#pragma unroll
    for (int c = 0; c < NCHUNK; c++) v[c] = base[c * 64];
    float run = 0.f;
#pragma unroll
    for (int c = 0; c < NCHUNK; c++) {
      float t = v[c];
      base[c * 64] = run;
      run += t;
    }
  }
}

// ---------------------------------------------------------------------------
// Phase 4: per (h,c): accO = Q.P ; S = Q K^T (causal) ; accO += S.V ;
// den = q.Skp + rowsum(S). All matmul operands from LDS; P/K share a region.
// ---------------------------------------------------------------------------
static __device__ void phase_attn(const P& p, int b, SH& sh) {
  constexpr int STR = 68;
  const int h = b >> 5, c = b & 31;
  const int tid = threadIdx.x;
  const int ty = tid >> 4, tx = tid & 15;
  const int r0 = ty * 4, c0 = tx * 4, m0 = tx * 4;
  const int t0 = c * CHUNK;
  const size_t cb = ((size_t)h * T_SEQ + t0) * DH;
  const float* Pg = p.Skv + (size_t)b * 4096;

  short4v kreg[4], greg[4];
  float ireg[4];
#pragma unroll
  for (int q = 0; q < 4; q++) {
    int f = q * 256 + tid, row = f >> 4, seg = (f & 15) * 4;
    kreg[q] = *(const short4v*)&p.Kb[cb + row * 64 + seg];
    greg[q] = *(const short4v*)&p.Gb[(size_t)(t0 + row) * DM + h * 64 + seg];
    ireg[q] = 1.f / (p.ga[t0 + row] * (1.f / DM) + 1e-5f);
  }
#pragma unroll
  for (int q = 0; q < 4; q++) {
    int f = q * 256 + tid, row = f >> 4, seg = (f & 15) * 4;
    short4v qr = *(const short4v*)&p.Qb[cb + row * 64 + seg];
    short4v gq = *(const short4v*)&p.Gb[(size_t)(t0 + row) * DM + h * 64 + seg];
    short4v vr = *(const short4v*)&p.Vb[cb + row * 64 + seg];
    const float inv = 1.f / (p.ga[t0 + row] * (1.f / DM) + 1e-5f);
    f32x4 qgv, vv;
#pragma unroll
    for (int e = 0; e < 4; e++) {
      qgv[e] = gelu1(b2f(qr[e]), b2f(gq[e]), inv);
      vv[e] = b2f(vr[e]);
    }
    *(f32x4*)&sh.at.Q[row * STR + seg] = qgv;
    *(f32x4*)&sh.at.V[row * STR + seg] = vv;
    *(f32x4*)&sh.at.KP[row * STR + seg] = *(const f32x4*)&Pg[row * 64 + seg];
  }
  if (tid < 64) sh.at.skp[tid] = p.Sk[b * 64 + tid];
  __syncthreads();  // B1

  if (tid < 64) {
    float s = 1e-5f;
#pragma unroll 4
    for (int d = 0; d < 64; d++) s += sh.at.Q[tid * STR + d] * sh.at.skp[d];
    sh.at.den[tid] = s;
  }

  float accO[4][4] = {};
#pragma unroll 2
  for (int d0 = 0; d0 < 64; d0 += 4) {
    f32x4 qf[4], pf[4];
#pragma unroll
    for (int i = 0; i < 4; i++) qf[i] = *(const f32x4*)&sh.at.Q[(r0 + i) * STR + d0];
#pragma unroll
    for (int dd = 0; dd < 4; dd++) pf[dd] = *(const f32x4*)&sh.at.KP[(d0 + dd) * STR + m0];
#pragma unroll
    for (int i = 0; i < 4; i++)
#pragma unroll
      for (int j = 0; j < 4; j++)
        accO[i][j] += qf[i][0] * pf[0][j] + qf[i][1] * pf[1][j] +
                      qf[i][2] * pf[2][j] + qf[i][3] * pf[3][j];
  }
  __syncthreads();  // B2
#pragma unroll
  for (int q = 0; q < 4; q++) {
    int f = q * 256 + tid, row = f >> 4, seg = (f & 15) * 4;
    f32x4 kgv;
#pragma unroll
    for (int e = 0; e < 4; e++) kgv[e] = gelu1(b2f(kreg[q][e]), b2f(greg[q][e]), ireg[q]);
    *(f32x4*)&sh.at.KP[row * STR + seg] = kgv;
  }
  __syncthreads();  // B3

  float accS[4][4] = {};
#pragma unroll 2
  for (int d0 = 0; d0 < 64; d0 += 4) {
    f32x4 qf[4], kf[4];
#pragma unroll
    for (int i = 0; i < 4; i++) qf[i] = *(const f32x4*)&sh.at.Q[(r0 + i) * STR + d0];
#pragma unroll
    for (int j = 0; j < 4; j++) kf[j] = *(const f32x4*)&sh.at.KP[(c0 + j) * STR + d0];
#pragma unroll
    for (int i = 0; i < 4; i++)
#pragma unroll
      for (int j = 0; j < 4; j++)
        accS[i][j] += qf[i][0] * kf[j][0] + qf[i][1] * kf[j][1] +
                      qf[i][2] * kf[j][2] + qf[i][3] * kf[j][3];
  }
  float dp[4];
#pragma unroll
  for (int i = 0; i < 4; i++) {
    dp[i] = 0.f;
#pragma unroll
    for (int j = 0; j < 4; j++) {
      float v = (c0 + j) <= (r0 + i) ? accS[i][j] : 0.f;
      accS[i][j] = v;
      dp[i] += v;
    }
  }
  __syncthreads();  // B4
#pragma unroll
  for (int i = 0; i < 4; i++) {
    f32x4 sv = {accS[i][0], accS[i][1], accS[i][2], accS[i][3]};
    *(f32x4*)&sh.at.Q[(r0 + i) * STR + c0] = sv;
    sh.at.denp[(r0 + i) * 16 + tx] = dp[i];
  }
  __syncthreads();  // B5
  if (tid < 64) {
    float s = sh.at.den[tid];
#pragma unroll
    for (int t = 0; t < 16; t++) s += sh.at.denp[tid * 16 + t];
    sh.at.den[tid] = s;
  }

#pragma unroll 2
  for (int c4 = 0; c4 < 64; c4 += 4) {
    f32x4 sf[4], vf[4];
#pragma unroll
    for (int i = 0; i < 4; i++) sf[i] = *(const f32x4*)&sh.at.Q[(r0 + i) * STR + c4];
#pragma unroll
    for (int cc = 0; cc < 4; cc++) vf[cc] = *(const f32x4*)&sh.at.V[(c4 + cc) * STR + m0];
#pragma unroll
    for (int i = 0; i < 4; i++)
#pragma unroll
      for (int j = 0; j < 4; j++)
        accO[i][j] += sf[i][0] * vf[0][j] + sf[i][1] * vf[1][j] +
                      sf[i][2] * vf[2][j] + sf[i][3] * vf[3][j];
  }
  __syncthreads();  // B6

#pragma unroll
  for (int i = 0; i < 4; i++) {
    const float inv = 1.f / sh.at.den[r0 + i];
    short4v ov;
#pragma unroll
    for (int j = 0; j < 4; j++) ov[j] = f2b_bits(accO[i][j] * inv);
    *(short4v*)&p.Obuf[(size_t)(t0 + r0 + i) * DM + h * 64 + m0] = ov;
  }
  __syncthreads();  // protect LDS before next phase overlays it
}

// ---------------------------------------------------------------------------
// Phase 5: proj GEMM, 64x64 tiles, BK=64, 512 tiles (bm=blk&31, bn=blk>>5).
// ---------------------------------------------------------------------------
static __device__ void phase_proj(const P& p, int blk, SH& sh) {
  constexpr int K = 1024;
  const int tid = threadIdx.x;
  const int wid = tid >> 6, lane = tid & 63;
  const int wm = wid >> 1, wn = wid & 1;   // wave tile 32x32
  const int lm = lane & 15, quad = lane >> 4;

  const int m0 = (blk & 31) * 64;
  const int n0 = (blk >> 5) * 64;
  const short* Ag = (const short*)p.Obuf;
  const short* Wg = (const short*)p.wproj;

  f32x4 zero = {0.f, 0.f, 0.f, 0.f};
  f32x4 acc[2][2];
#pragma unroll
  for (int i = 0; i < 2; i++)
#pragma unroll
    for (int j = 0; j < 2; j++) acc[i][j] = zero;

  for (int kb = 0; kb < K; kb += 64) {
    __syncthreads();
#pragma unroll
    for (int sec = 0; sec < 2; sec++) {
      const int row = tid >> 2, seg = (tid & 3) * 8;
      gload16(&Ag[(size_t)(m0 + row) * K + kb + sec * 32 + seg],
              &sh.pj.A[sec * 2048 + wid * 512]);
      gload16(&Wg[(size_t)(n0 + row) * K + kb + sec * 32 + seg],
              &sh.pj.B[sec * 2048 + wid * 512]);
    }
    __syncthreads();
#pragma unroll
    for (int sec = 0; sec < 2; sec++) {
      short8 afr[2], bfr[2];
#pragma unroll
      for (int i = 0; i < 2; i++)
        afr[i] = *(const short8*)&sh.pj.A[sec * 2048 + (wm * 32 + i * 16 + lm) * 32 + quad * 8];
#pragma unroll
      for (int j = 0; j < 2; j++)
        bfr[j] = *(const short8*)&sh.pj.B[sec * 2048 + (wn * 32 + j * 16 + lm) * 32 + quad * 8];
#pragma unroll
      for (int i = 0; i < 2; i++)
#pragma unroll
        for (int j = 0; j < 2; j++)
          acc[i][j] = __builtin_amdgcn_mfma_f32_16x16x32_bf16(afr[i], bfr[j], acc[i][j], 0, 0, 0);
    }
  }
#pragma unroll
  for (int i = 0; i < 2; i++) {
    const int rbase = m0 + wm * 32 + i * 16 + quad * 4;
#pragma unroll
    for (int j = 0; j < 2; j++) {
      const int col = n0 + wn * 32 + j * 16 + lm;
      const float bval = p.proj_b[col];
#pragma unroll
      for (int r = 0; r < 4; r++)
        p.out[(size_t)(rbase + r) * DM + col] = acc[i][j][r] + bval;
    }
  }
}

// ---------------------------------------------------------------------------
// Cooperative mega-kernel: all phases, grid.sync() between (5 boundaries -> 0).
// ---------------------------------------------------------------------------
__global__ __launch_bounds__(256, 2) void mega_kernel(P p) {
  __shared__ __align__(16) SH sh;
  cg::grid_group grid = cg::this_grid();
  const int blk = blockIdx.x;
  phase_prep(p, blk, sh);
  grid.sync();
  phase_gemm1(p, blk, sh);
  grid.sync();
  phase_csum(p, blk, sh);
  grid.sync();
  phase_scan(p, blk);
  grid.sync();
  phase_attn(p, blk, sh);
  grid.sync();
  phase_proj(p, blk, sh);
}

// Fallback: identical phases as 6 separate launches (if coop launch refused).
__global__ __launch_bounds__(256) void k_prep(P p)  { __shared__ __align__(16) SH sh; phase_prep(p, blockIdx.x, sh); }
__global__ __launch_bounds__(256) void k_gemm1(P p) { __shared__ __align__(16) SH sh; phase_gemm1(p, blockIdx.x, sh); }
__global__ __launch_bounds__(256) void k_csum(P p)  { __shared__ __align__(16) SH sh; phase_csum(p, blockIdx.x, sh); }
__global__ __launch_bounds__(256) void k_scan(P p)  { phase_scan(p, blockIdx.x); }
__global__ __launch_bounds__(256) void k_attn(P p)  { __shared__ __align__(16) SH sh; phase_attn(p, blockIdx.x, sh); }
__global__ __launch_bounds__(256) void k_proj(P p)  { __shared__ __align__(16) SH sh; phase_proj(p, blockIdx.x, sh); }

// ---------------------------------------------------------------------------
extern "C" void kernel_launch(void* const* d_in, const int* in_sizes, int n_in,
                              void* d_out, int out_size, void* d_ws, size_t ws_size,
                              hipStream_t stream) {
  (void)in_sizes; (void)n_in; (void)out_size; (void)ws_size;
  char* ws = (char*)d_ws;
  size_t off = 0;
  auto alloc = [&](size_t bytes) {
    void* pp = ws + off;
    off += (bytes + 255) & ~(size_t)255;
    return pp;
  };
  P p;
  p.x      = (const float*)d_in[0];
  p.ln_g   = (const float*)d_in[1];
  p.ln_b   = (const float*)d_in[2];
  p.qkv_w  = (const float*)d_in[3];
  p.qkv_b  = (const float*)d_in[4];
  p.gate_w = (const float*)d_in[5];
  p.gate_b = (const float*)d_in[6];
  p.proj_w = (const float*)d_in[7];
  p.proj_b = (const float*)d_in[8];
  p.out    = (float*)d_out;
  p.xn     = (bf16*)alloc((size_t)T_SEQ * DM * 2);
  p.xbf    = (bf16*)alloc((size_t)T_SEQ * DM * 2);
  p.wqkv   = (bf16*)alloc((size_t)3 * DM * DM * 2);
  p.wgate  = (bf16*)alloc((size_t)DM * DM * 2);
  p.wproj  = (bf16*)alloc((size_t)DM * DM * 2);
  p.Gb     = (short*)alloc((size_t)T_SEQ * DM * 2);
  p.ga     = (float*)alloc((size_t)T_SEQ * 4);
  p.Qb     = (short*)alloc((size_t)T_SEQ * DM * 2);
  p.Kb     = (short*)alloc((size_t)T_SEQ * DM * 2);
  p.Vb     = (short*)alloc((size_t)T_SEQ * DM * 2);
  p.Obuf   = (bf16*)alloc((size_t)T_SEQ * DM * 2);
  p.Skv    = (float*)alloc((size_t)NH * NCHUNK * 4096 * 4);
  p.Sk     = (float*)alloc((size_t)NH * NCHUNK * 64 * 4);

  void* args[] = {&p};
  hipError_t e = hipLaunchCooperativeKernel((void*)mega_kernel, dim3(NBLK), dim3(256),
                                            args, 0, stream);
  if (e != hipSuccess) {
    (void)hipGetLastError();  // clear
    k_prep<<<NBLK, 256, 0, stream>>>(p);
    k_gemm1<<<NBLK, 256, 0, stream>>>(p);
    k_csum<<<NBLK, 256, 0, stream>>>(p);
    k_scan<<<260, 256, 0, stream>>>(p);
    k_attn<<<NBLK, 256, 0, stream>>>(p);
    k_proj<<<NBLK, 256, 0, stream>>>(p);
  }
}